// Round 1
// baseline (212.023 us; speedup 1.0000x reference)
//
#include <hip/hip_runtime.h>

typedef __bf16 bf16x8 __attribute__((ext_vector_type(8)));
typedef __bf16 bf16x4 __attribute__((ext_vector_type(4)));
typedef float  f32x4  __attribute__((ext_vector_type(4)));

// ---- LDS layout (bytes) ----
// x_lds : [96][256] bf16, swizzled  off = ((m*512 + 2c)) ^ ((m&7)<<4)        [0, 49152)
// y_lds : [32][768] bf16, swizzled  off = ((p*1536 + 2kk)) ^ ((p&7)<<4)      aliases x_lds (written after LN)
// qkv   : [96][104] bf16 (padded rows, no swizzle)                           [49152, 69120)
// o_h   : [96][32]  bf16, swizzled  off = ((m*64 + 2d)) ^ ((m&7)<<4)         [69120, 75264)
// part_s: [96][4] f32                                                        [75264, 76800)
// part_q: [96][4] f32                                                        [76800, 78336)
// mean  : [96] f32                                                           [78336, 78720)
// rstd  : [96] f32                                                           [78720, 79104)
#define XOFF   0
#define QKVOFF 49152
#define OOFF   69120
#define PSOFF  75264
#define PQOFF  76800
#define MUOFF  78336
#define RSOFF  78720
#define SMEM_BYTES 79104

static __device__ __forceinline__ unsigned short f2b(float f) {
  __bf16 h = (__bf16)f;
  return __builtin_bit_cast(unsigned short, h);
}

__global__ void convert_weights(const float* __restrict__ w_in,
                                const float* __restrict__ w_out,
                                const float* __restrict__ w_conv,
                                __bf16* __restrict__ ws) {
  int gid = blockIdx.x * 256 + threadIdx.x;   // 0..114687
  int i4 = gid * 4;
  const float* src;
  int off;
  if (i4 < 196608)      { src = w_in;   off = i4; }
  else if (i4 < 262144) { src = w_out;  off = i4 - 196608; }
  else                  { src = w_conv; off = i4 - 262144; }
  float4 f = *(const float4*)(src + off);
  ws[i4 + 0] = (__bf16)f.x;
  ws[i4 + 1] = (__bf16)f.y;
  ws[i4 + 2] = (__bf16)f.z;
  ws[i4 + 3] = (__bf16)f.w;
}

__global__ __launch_bounds__(256, 2) void crf_fused(
    const float* __restrict__ cort,
    const float* __restrict__ subc,
    const float* __restrict__ vent,
    const __bf16* __restrict__ w_in,
    const float* __restrict__ b_in,
    const __bf16* __restrict__ w_out,
    const float* __restrict__ b_out,
    const float* __restrict__ gamma,
    const float* __restrict__ beta,
    const __bf16* __restrict__ w_conv,
    const float* __restrict__ b_conv,
    float* __restrict__ out) {
  extern __shared__ char smem[];
  const int tid  = threadIdx.x;
  const int lane = tid & 63;
  const int wv   = tid >> 6;
  const int l15  = lane & 15;
  const int l4   = lane >> 4;
  const int blk  = blockIdx.x;
  const int img  = blk >> 7;                 // 128 blocks per image
  const int pixbase = (blk & 127) << 5;      // 32 pixels per block
  const size_t base = (size_t)img * (256 * 4096) + pixbase;

  // ---------- Phase 0: stage x -> LDS bf16 [96][256] swizzled ----------
  {
    const float* rp0 = cort + base;
    const float* rp1 = subc + base;
    const float* rp2 = vent + base;
#pragma unroll
    for (int si = 0; si < 3; ++si) {
      const float* rp = (si == 0) ? rp0 : (si == 1) ? rp1 : rp2;
#pragma unroll
      for (int t = 0; t < 16; ++t) {
        int idx = t * 256 + tid;        // 0..4095
        int p   = idx & 31;
        int c   = (idx >> 5) * 2;       // even channel
        float f0 = rp[(size_t)c * 4096 + p];
        float f1 = rp[(size_t)(c + 1) * 4096 + p];
        int m = si * 32 + p;
        unsigned off = ((unsigned)(m * 512 + c * 2)) ^ ((unsigned)(m & 7) << 4);
        unsigned pack = (unsigned)f2b(f0) | ((unsigned)f2b(f1) << 16);
        *(unsigned*)(smem + XOFF + off) = pack;
      }
    }
  }

  f32x4 accY[6][4] = {};   // persistent out_proj accumulators (wave owns 4 N-tiles, all 6 M-tiles)

  __syncthreads();

  const int wm = wv >> 1;  // M half for QKV
  const int wn = wv & 1;   // N half for QKV

  for (int h = 0; h < 8; ++h) {
    // ---------- Phase A: QKV GEMM, head h. M=96 tok, N=96 (q|k|v 32 each), K=256 ----------
    {
      f32x4 accQ[3][3] = {};
#pragma unroll
      for (int ks = 0; ks < 8; ++ks) {
        int k0 = ks * 32;
        bf16x8 af[3], bfr[3];
#pragma unroll
        for (int i = 0; i < 3; ++i) {
          int m = (wm * 3 + i) * 16 + l15;
          int kk = k0 + l4 * 8;
          unsigned off = ((unsigned)(m * 512 + kk * 2)) ^ ((unsigned)(m & 7) << 4);
          af[i] = *(const bf16x8*)(smem + XOFF + off);
        }
#pragma unroll
        for (int j = 0; j < 3; ++j) {
          int tn = wn * 3 + j;
          int jb = (tn >> 1) * 256 + h * 32 + (tn & 1) * 16;
          bfr[j] = *(const bf16x8*)(w_in + (size_t)(jb + l15) * 256 + k0 + l4 * 8);
        }
#pragma unroll
        for (int i = 0; i < 3; ++i)
#pragma unroll
          for (int j = 0; j < 3; ++j)
            accQ[i][j] = __builtin_amdgcn_mfma_f32_16x16x32_bf16(af[i], bfr[j], accQ[i][j], 0, 0, 0);
      }
      // write qkv (+bias) to LDS [96][104]
#pragma unroll
      for (int j = 0; j < 3; ++j) {
        int tn = wn * 3 + j;
        int jb = (tn >> 1) * 256 + h * 32 + (tn & 1) * 16;
        float bias = b_in[jb + l15];
        int n = tn * 16 + l15;
#pragma unroll
        for (int i = 0; i < 3; ++i)
#pragma unroll
          for (int r = 0; r < 4; ++r) {
            int m = (wm * 3 + i) * 16 + l4 * 4 + r;
            *(__bf16*)(smem + QKVOFF + (m * 104 + n) * 2) = (__bf16)(accQ[i][j][r] + bias);
          }
      }
    }
    __syncthreads();

    // ---------- Phase B: attention, head h. thread = (pixel p, d-slice sl of 4) ----------
    {
      int p  = tid >> 3;
      int sl = tid & 7;
      float qf[3][4], kf[3][4], vf[3][4];
#pragma unroll
      for (int s = 0; s < 3; ++s) {
        const char* row = smem + QKVOFF + (s * 32 + p) * 208;
        bf16x4 q4 = *(const bf16x4*)(row + sl * 8);
        bf16x4 k4 = *(const bf16x4*)(row + 64 + sl * 8);
        bf16x4 v4 = *(const bf16x4*)(row + 128 + sl * 8);
#pragma unroll
        for (int d = 0; d < 4; ++d) {
          qf[s][d] = (float)q4[d];
          kf[s][d] = (float)k4[d];
          vf[s][d] = (float)v4[d];
        }
      }
      float sc[3][3];
#pragma unroll
      for (int s = 0; s < 3; ++s)
#pragma unroll
        for (int t2 = 0; t2 < 3; ++t2) {
          float d0 = qf[s][0]*kf[t2][0] + qf[s][1]*kf[t2][1] + qf[s][2]*kf[t2][2] + qf[s][3]*kf[t2][3];
          d0 += __shfl_xor(d0, 1);
          d0 += __shfl_xor(d0, 2);
          d0 += __shfl_xor(d0, 4);
          sc[s][t2] = d0 * 0.17677669529663687f;   // 1/sqrt(32)
        }
      float ov[3][4];
#pragma unroll
      for (int s = 0; s < 3; ++s) {
        float mx = fmaxf(sc[s][0], fmaxf(sc[s][1], sc[s][2]));
        float e0 = __expf(sc[s][0] - mx);
        float e1 = __expf(sc[s][1] - mx);
        float e2 = __expf(sc[s][2] - mx);
        float inv = 1.f / (e0 + e1 + e2);
        e0 *= inv; e1 *= inv; e2 *= inv;
#pragma unroll
        for (int d = 0; d < 4; ++d)
          ov[s][d] = e0 * vf[0][d] + e1 * vf[1][d] + e2 * vf[2][d];
      }
#pragma unroll
      for (int s = 0; s < 3; ++s) {
        int m = s * 32 + p;
        bf16x4 o4;
#pragma unroll
        for (int d = 0; d < 4; ++d) o4[d] = (__bf16)ov[s][d];
        unsigned off = ((unsigned)(m * 64 + sl * 8)) ^ ((unsigned)(m & 7) << 4);
        *(bf16x4*)(smem + OOFF + off) = o4;
      }
    }
    __syncthreads();

    // ---------- Phase C: out_proj partial, K-slice [h*32, h*32+32) ----------
    {
      bf16x8 af[6], bfr[4];
#pragma unroll
      for (int i = 0; i < 6; ++i) {
        int m = i * 16 + l15;
        unsigned off = ((unsigned)(m * 64 + l4 * 16)) ^ ((unsigned)(m & 7) << 4);
        af[i] = *(const bf16x8*)(smem + OOFF + off);
      }
#pragma unroll
      for (int j = 0; j < 4; ++j) {
        int jr = (wv * 4 + j) * 16 + l15;
        bfr[j] = *(const bf16x8*)(w_out + (size_t)jr * 256 + h * 32 + l4 * 8);
      }
#pragma unroll
      for (int i = 0; i < 6; ++i)
#pragma unroll
        for (int j = 0; j < 4; ++j)
          accY[i][j] = __builtin_amdgcn_mfma_f32_16x16x32_bf16(af[i], bfr[j], accY[i][j], 0, 0, 0);
    }
    __syncthreads();
  }  // head loop

  // ---------- Phase D: bias + residual + LayerNorm ----------
  float bo[4], gg[4], bb[4];
#pragma unroll
  for (int j = 0; j < 4; ++j) {
    int jc = (wv * 4 + j) * 16 + l15;
    bo[j] = b_out[jc];
    gg[j] = gamma[jc];
    bb[j] = beta[jc];
  }
#pragma unroll
  for (int i = 0; i < 6; ++i)
#pragma unroll
    for (int r = 0; r < 4; ++r) {
      int m = i * 16 + l4 * 4 + r;
      float s1 = 0.f, s2 = 0.f;
#pragma unroll
      for (int j = 0; j < 4; ++j) {
        int jc = (wv * 4 + j) * 16 + l15;
        unsigned xo = ((unsigned)(m * 512 + jc * 2)) ^ ((unsigned)(m & 7) << 4);
        float xv = (float)(*(const __bf16*)(smem + XOFF + xo));
        float v = accY[i][j][r] + bo[j] + xv;
        accY[i][j][r] = v;
        s1 += v;
        s2 += v * v;
      }
      s1 += __shfl_xor(s1, 1); s2 += __shfl_xor(s2, 1);
      s1 += __shfl_xor(s1, 2); s2 += __shfl_xor(s2, 2);
      s1 += __shfl_xor(s1, 4); s2 += __shfl_xor(s2, 4);
      s1 += __shfl_xor(s1, 8); s2 += __shfl_xor(s2, 8);
      if (l15 == 0) {
        *(float*)(smem + PSOFF + (m * 4 + wv) * 4) = s1;
        *(float*)(smem + PQOFF + (m * 4 + wv) * 4) = s2;
      }
    }
  __syncthreads();
  if (tid < 96) {
    float s = 0.f, q = 0.f;
#pragma unroll
    for (int j = 0; j < 4; ++j) {
      s += *(const float*)(smem + PSOFF + (tid * 4 + j) * 4);
      q += *(const float*)(smem + PQOFF + (tid * 4 + j) * 4);
    }
    float mu  = s * (1.f / 256.f);
    float var = q * (1.f / 256.f) - mu * mu;
    *(float*)(smem + MUOFF + tid * 4) = mu;
    *(float*)(smem + RSOFF + tid * 4) = rsqrtf(var + 1e-5f);
  }
  __syncthreads();
  // rescale + write y bf16 into [32][768] (aliases x region; all x reads done pre-barrier)
#pragma unroll
  for (int i = 0; i < 6; ++i)
#pragma unroll
    for (int r = 0; r < 4; ++r) {
      int m = i * 16 + l4 * 4 + r;
      float mu = *(const float*)(smem + MUOFF + m * 4);
      float rs = *(const float*)(smem + RSOFF + m * 4);
      int s = m >> 5, p = m & 31;
#pragma unroll
      for (int j = 0; j < 4; ++j) {
        int jc = (wv * 4 + j) * 16 + l15;
        float yv = (accY[i][j][r] - mu) * rs * gg[j] + bb[j];
        int kk = s * 256 + jc;
        unsigned off = ((unsigned)(p * 1536 + kk * 2)) ^ ((unsigned)(p & 7) << 4);
        *(__bf16*)(smem + XOFF + off) = (__bf16)yv;
      }
    }
  __syncthreads();

  // ---------- Phase E: 1x1 conv. M=cout(256), N=pixel(32), K=768 ----------
  {
    f32x4 accC[4][2] = {};
#pragma unroll 4
    for (int ks = 0; ks < 24; ++ks) {
      int k0 = ks * 32;
      bf16x8 af[4], bfr2[2];
#pragma unroll
      for (int i = 0; i < 4; ++i) {
        int co = (wv * 4 + i) * 16 + l15;
        af[i] = *(const bf16x8*)(w_conv + (size_t)co * 768 + k0 + l4 * 8);
      }
#pragma unroll
      for (int j = 0; j < 2; ++j) {
        int p = j * 16 + l15;
        int kk = k0 + l4 * 8;
        unsigned off = ((unsigned)(p * 1536 + kk * 2)) ^ ((unsigned)(p & 7) << 4);
        bfr2[j] = *(const bf16x8*)(smem + XOFF + off);
      }
#pragma unroll
      for (int i = 0; i < 4; ++i)
#pragma unroll
        for (int j = 0; j < 2; ++j)
          accC[i][j] = __builtin_amdgcn_mfma_f32_16x16x32_bf16(af[i], bfr2[j], accC[i][j], 0, 0, 0);
    }
#pragma unroll
    for (int i = 0; i < 4; ++i)
#pragma unroll
      for (int r = 0; r < 4; ++r) {
        int co = (wv * 4 + i) * 16 + l4 * 4 + r;
        float cb = b_conv[co];
#pragma unroll
        for (int j = 0; j < 2; ++j) {
          int pix = pixbase + j * 16 + l15;
          out[((size_t)img * 256 + co) * 4096 + pix] = accC[i][j][r] + cb;
        }
      }
  }
}

extern "C" void kernel_launch(void* const* d_in, const int* in_sizes, int n_in,
                              void* d_out, int out_size, void* d_ws, size_t ws_size,
                              hipStream_t stream) {
  (void)in_sizes; (void)n_in; (void)out_size; (void)ws_size;
  const float* cort    = (const float*)d_in[0];
  const float* subc    = (const float*)d_in[1];
  const float* vent    = (const float*)d_in[2];
  const float* w_in_f  = (const float*)d_in[3];
  const float* b_in    = (const float*)d_in[4];
  const float* w_out_f = (const float*)d_in[5];
  const float* b_out   = (const float*)d_in[6];
  const float* gamma   = (const float*)d_in[7];
  const float* beta    = (const float*)d_in[8];
  const float* w_conv_f= (const float*)d_in[9];
  const float* b_conv  = (const float*)d_in[10];

  __bf16* ws = (__bf16*)d_ws;   // needs 458752 bf16 = 917504 B
  convert_weights<<<448, 256, 0, stream>>>(w_in_f, w_out_f, w_conv_f, ws);
  crf_fused<<<1024, 256, SMEM_BYTES, stream>>>(
      cort, subc, vent,
      ws,            b_in,
      ws + 196608,   b_out,
      gamma,         beta,
      ws + 262144,   b_conv,
      (float*)d_out);
}